// Round 5
// baseline (44.352 us; speedup 1.0000x reference)
//
#include <hip/hip_runtime.h>
#include <math.h>

#define BB 32
#define SS 4
#define TT 4000
#define FF 96
#define FRAMES (BB * TT)        // 128000
#define FPG 16                  // frames per 32-lane group (16 | 4000, no b-crossing)
#define GROUPS (FRAMES / FPG)   // 8000
#define NBLOCKS (GROUPS / 8)    // 1000

// ws layout: float4 partial[NBLOCKS] = {bce_sum, corr, fa, ms}
__global__ __launch_bounds__(256) void frame_kernel(
    const float* __restrict__ x, const float* __restrict__ labels,
    const float* __restrict__ W, const float* __restrict__ bias,
    float4* __restrict__ partial)
{
    const int tid = threadIdx.x;
    const int sub = tid & 31;       // lane within 32-lane frame group
    const int s   = sub >> 3;       // 0..3  (the S dimension)
    const int l8  = sub & 7;        // lane within 8-lane row group
    const int g   = tid >> 5;       // frame-group within block (0..7)
    const unsigned int group = blockIdx.x * 8u + (unsigned int)g;   // 0..7999

    // group owns frames [group*16, group*16+16); 16 | 4000 so chunk stays in one b
    const unsigned int b  = group / 250u;
    const unsigned int t0 = (group - b * 250u) * FPG;

    const float4* W4 = reinterpret_cast<const float4*>(W);
    const float4 w0 = W4[l8];
    const float4 w1 = W4[l8 + 8];
    const float4 w2 = W4[l8 + 16];
    const float bval = bias[0];

    const unsigned int rowb = (b * 4u + (unsigned int)s) * (unsigned int)TT + t0;
    const float4* xb = reinterpret_cast<const float4*>(x) + (size_t)rowb * 24 + l8;

    // labels: rowb multiple of 16 -> 64B aligned -> four float4 loads
    const float4* lp4 = reinterpret_cast<const float4*>(labels + rowb);
    const float4 labA = lp4[0];
    const float4 labB = lp4[1];
    const float4 labC = lp4[2];
    const float4 labD = lp4[3];
    const float labarr[16] = {labA.x, labA.y, labA.z, labA.w,
                              labB.x, labB.y, labB.z, labB.w,
                              labC.x, labC.y, labC.z, labC.w,
                              labD.x, labD.y, labD.z, labD.w};

    float bsum = 0.0f;                    // x8 replicated (all 8 lanes)
    int c_corr = 0, c_fa = 0, c_ms = 0;   // x32 replicated (all 32 lanes)

    #pragma unroll
    for (int q = 0; q < 4; ++q) {
        float4 xv[4][3];
        #pragma unroll
        for (int u = 0; u < 4; ++u) {
            const int j = q * 4 + u;
            const float4* xr = xb + j * 24;
            xv[u][0] = xr[0];             // 128B contiguous per 8-lane group
            xv[u][1] = xr[8];
            xv[u][2] = xr[16];
        }
        #pragma unroll
        for (int u = 0; u < 4; ++u) {
            const int j = q * 4 + u;
            float p = xv[u][0].x * w0.x + xv[u][0].y * w0.y + xv[u][0].z * w0.z + xv[u][0].w * w0.w
                    + xv[u][1].x * w1.x + xv[u][1].y * w1.y + xv[u][1].z * w1.z + xv[u][1].w * w1.w
                    + xv[u][2].x * w2.x + xv[u][2].y * w2.y + xv[u][2].z * w2.z + xv[u][2].w * w2.w;
            p += __shfl_xor(p, 1);
            p += __shfl_xor(p, 2);
            p += __shfl_xor(p, 4);

            const float logit = p + bval;
            const float lab = labarr[j];
            const int pred = (logit > 0.0f) ? 1 : 0;

            // stable softplus: max(z,0) + log1p(exp(-|z|))
            const float sp = fmaxf(logit, 0.0f) + log1pf(expf(-fabsf(logit)));
            bsum += sp - logit * lab;

            const int eq = ((pred ? 1.0f : 0.0f) == lab) ? 1 : 0;
            const int lz = (lab == 0.0f) ? 1 : 0;
            const int pz = pred ? 0 : 1;
            int f = eq | (lz << 1) | (pz << 2);
            f &= __shfl_xor(f, 8);
            f &= __shfl_xor(f, 16);

            const int match = f & 1;
            const int flz = (f >> 1) & 1;
            const int fpz = (f >> 2) & 1;
            c_corr += match;
            c_fa   += (!match) & flz;
            c_ms   += (!match) & (!flz) & fpz;
        }
    }

    // wave-wide butterfly reduce (64 lanes)
    int ic = c_corr, ifa = c_fa, ims = c_ms;
    for (int m = 1; m < 64; m <<= 1) {
        bsum += __shfl_xor(bsum, m);
        ic   += __shfl_xor(ic, m);
        ifa  += __shfl_xor(ifa, m);
        ims  += __shfl_xor(ims, m);
    }

    __shared__ float s_sum[4];
    __shared__ int s_c[4][3];
    const int wave = tid >> 6;
    if ((tid & 63) == 0) {
        s_sum[wave] = bsum;
        s_c[wave][0] = ic; s_c[wave][1] = ifa; s_c[wave][2] = ims;
    }
    __syncthreads();
    if (tid == 0) {
        float tot = 0.0f;
        int tc = 0, tf = 0, tm = 0;
        for (int w = 0; w < 4; ++w) {
            tot += s_sum[w];
            tc += s_c[w][0]; tf += s_c[w][1]; tm += s_c[w][2];
        }
        // per-block counts <= 128, exact in fp32
        partial[blockIdx.x] = make_float4(tot * 0.125f,        // undo x8 replication
                                          (float)(tc >> 5),    // undo x32 replication
                                          (float)(tf >> 5),
                                          (float)(tm >> 5));
    }
}

__global__ __launch_bounds__(256) void finalize_kernel(
    const float4* __restrict__ partial, float* __restrict__ out)
{
    const int tid = threadIdx.x;

    double sum = 0.0;
    int tc = 0, tf = 0, tm = 0;
    for (int i = tid; i < NBLOCKS; i += 256) {
        const float4 p = partial[i];
        sum += (double)p.x;
        tc += (int)p.y; tf += (int)p.z; tm += (int)p.w;
    }
    for (int m = 1; m < 64; m <<= 1) {
        sum += __shfl_xor(sum, m);
        tc  += __shfl_xor(tc, m);
        tf  += __shfl_xor(tf, m);
        tm  += __shfl_xor(tm, m);
    }
    __shared__ double s_sum[4];
    __shared__ int s_c[4][3];
    const int wave = tid >> 6;
    if ((tid & 63) == 0) {
        s_sum[wave] = sum;
        s_c[wave][0] = tc; s_c[wave][1] = tf; s_c[wave][2] = tm;
    }
    __syncthreads();
    if (tid != 0) return;

    double Ssum = 0.0;
    int C_i = 0, FA_i = 0, MS_i = 0;
    for (int w = 0; w < 4; ++w) {
        Ssum += s_sum[w];
        C_i += s_c[w][0]; FA_i += s_c[w][1]; MS_i += s_c[w][2];
    }

    const double BT = (double)FRAMES;
    const double total_loss = Ssum / BT + Ssum / 4.0;
    const double loss = total_loss / BT;

    double C  = (double)C_i;
    double FA = (double)FA_i;
    double MS = (double)MS_i;
    double SC = BT - C - FA - MS;

    // replicate the reference's sequential normalization order exactly
    const double d0 = MS + FA + SC + C;
    const double DER = (MS + FA + SC) / d0;
    MS = MS / d0;
    const double d1 = MS + FA + SC + C;
    FA = FA / d1;
    const double d2 = MS + FA + SC + C;
    SC = SC / d2;

    out[0] = (float)loss;
    out[1] = (float)DER;
    out[2] = (float)MS;
    out[3] = (float)FA;
    out[4] = (float)SC;
}

extern "C" void kernel_launch(void* const* d_in, const int* in_sizes, int n_in,
                              void* d_out, int out_size, void* d_ws, size_t ws_size,
                              hipStream_t stream) {
    const float* x      = (const float*)d_in[0];
    const float* labels = (const float*)d_in[1];
    const float* W      = (const float*)d_in[2];
    const float* bias   = (const float*)d_in[3];
    float* out = (float*)d_out;

    float4* partial = (float4*)d_ws;   // 16 KB; every slot written each call

    frame_kernel<<<NBLOCKS, 256, 0, stream>>>(x, labels, W, bias, partial);
    finalize_kernel<<<1, 256, 0, stream>>>(partial, out);
}